// Round 4
// baseline (229.545 us; speedup 1.0000x reference)
//
#include <hip/hip_runtime.h>
#include <hip/hip_bf16.h>

#define NB 2
#define NN 20000
#define NKN 16          // neighbors per node
#define NC 128          // C_IN
#define NM 9            // M kernels
#define NO 128          // C_OUT
#define NR (NB*NN)      // 40000 rows
#define KK (NM*NC)      // 1152 GEMM reduce dim
#define NKC (KK/32)     // 36 K-chunks of 32
#define NPB 32          // nodes per fused block (20000 % 32 == 0 -> no batch straddle)
#define SROW 1160       // padded S-tile row in shorts (1152 + 8): stride%32banks=4 -> spread

#define AS1 __attribute__((address_space(1)))
#define AS3 __attribute__((address_space(3)))

typedef short bf16x8 __attribute__((ext_vector_type(8)));
typedef float f32x4 __attribute__((ext_vector_type(4)));
typedef unsigned short u16x8 __attribute__((ext_vector_type(8)));

__device__ inline float bf2f(unsigned short h) {
    union { unsigned int u; float f; } v; v.u = ((unsigned int)h) << 16; return v.f;
}

// ---------------- Kernel 1: prep = ycalc (+xb emit) | wprep, by block range ----------
// blocks [0, NR/4): y[r][m] = dot(x[r,:], u[m,:]), xb = bf16(x)
// blocks [NR/4, NR/4+576): Wg relayout (1152*128 elems)
__global__ __launch_bounds__(256) void prep_kernel(const float* __restrict__ x,
                                                   const float* __restrict__ u,
                                                   const float* __restrict__ W,
                                                   float* __restrict__ y,
                                                   __hip_bfloat16* __restrict__ xb,
                                                   __hip_bfloat16* __restrict__ Wg,
                                                   int use_xb) {
    if (blockIdx.x < NR / 4) {
        __shared__ float u_l[NM * NC];
        for (int t = threadIdx.x; t < NM * NC; t += 256) u_l[t] = u[t];
        __syncthreads();
        int wave = threadIdx.x >> 6;
        int lane = threadIdx.x & 63;
        int node = blockIdx.x * 4 + wave;
        float xv0 = x[node * NC + lane];
        float xv1 = x[node * NC + 64 + lane];
        if (use_xb) {
            xb[node * NC + lane]      = __float2bfloat16(xv0);
            xb[node * NC + 64 + lane] = __float2bfloat16(xv1);
        }
        #pragma unroll
        for (int m = 0; m < NM; m++) {
            float p = xv0 * u_l[m * NC + lane] + xv1 * u_l[m * NC + 64 + lane];
            #pragma unroll
            for (int off = 32; off > 0; off >>= 1) p += __shfl_xor(p, off, 64);
            if (lane == 0) y[node * NM + m] = p;
        }
    } else {
        // Wg[((kk/32)*128 + o)*32 + (kk%32)] = bf16(W[m][o][c]), kk = m*128+c
        int t = (blockIdx.x - NR / 4) * 256 + threadIdx.x;   // t < 1152*128
        int kk = t >> 7;
        int o = t & 127;
        int m = kk >> 7;
        int c = kk & 127;
        float v = W[m * 16384 + o * 128 + c];
        Wg[((kk >> 5) * 128 + o) * 32 + (kk & 31)] = __float2bfloat16(v);
    }
}

// ---------------- Kernel 2: fused edge-softmax + aggregate + MFMA GEMM --------------
// Block = 32 nodes, 512 threads (8 waves).
// Phase A: logits via Y-trick, softmax, deg_inv, gather-accumulate S'(32x1152) -> LDS bf16.
// Phase B: out[32x128] = S' x Wg + b via mfma_f32_16x16x32_bf16; Wg k-chunks (8KB)
//          staged via global_load_lds width=16, double-buffered.
template<bool BF16G>
__global__ __launch_bounds__(512, 2) void fused_kernel(const float* __restrict__ x,
                                                       const __hip_bfloat16* __restrict__ xb,
                                                       const int* __restrict__ adj,
                                                       const float* __restrict__ y,
                                                       const float* __restrict__ cv,
                                                       const __hip_bfloat16* __restrict__ Wg,
                                                       const float* __restrict__ bv,
                                                       float* __restrict__ out) {
    __shared__ short s_S[NPB][SROW];               // 74,240 B  S' tile (bf16)
    __shared__ __align__(16) short sB[2][4096];    // 16,384 B  B chunk double-buffer
    __shared__ int   s_adj[NPB][NKN];              //  2,048 B
    __shared__ float s_q[NPB][NKN][NM];            // 18,432 B
    __shared__ float s_di[NPB];                    //    128 B

    int tid = threadIdx.x;
    int node0 = blockIdx.x * NPB;
    int b = node0 / NN;
    int n0 = node0 - b * NN;
    const short* wg = reinterpret_cast<const short*>(Wg);
    int wave = tid >> 6;

    // early-issue: stage B chunk 0 into sB[0] (overlaps with phase A)
    {
        const short* src = wg + tid * 8;
        __builtin_amdgcn_global_load_lds((const AS1 void*)src,
                                         (AS3 void*)&sB[0][wave * 512], 16, 0, 0);
    }

    int ln = tid >> 4, k = tid & 15;               // 512 = 32 nodes x 16 edges
    s_adj[ln][k] = adj[(n0 + ln) * NKN + k];
    __syncthreads();

    {   // phase A2: logits (Y-trick) + softmax for edge (ln, k)
        int a = s_adj[ln][k];
        const float* yn = y + (node0 + ln) * NM;
        float l[NM];
        if (a != 0) {
            const float* ya = y + (long)(b * NN + a - 1) * NM;
            #pragma unroll
            for (int m = 0; m < NM; m++) l[m] = yn[m] - ya[m] + cv[m];
        } else {
            #pragma unroll
            for (int m = 0; m < NM; m++) l[m] = yn[m] + cv[m];
        }
        float mx = l[0];
        #pragma unroll
        for (int m = 1; m < NM; m++) mx = fmaxf(mx, l[m]);
        float e[NM]; float sum = 0.f;
        #pragma unroll
        for (int m = 0; m < NM; m++) { e[m] = expf(l[m] - mx); sum += e[m]; }
        float inv = 1.f / sum;
        #pragma unroll
        for (int m = 0; m < NM; m++) s_q[ln][k][m] = e[m] * inv;
    }
    if (tid < NPB) {
        int d = 0;
        #pragma unroll
        for (int kk2 = 0; kk2 < NKN; kk2++) d += (s_adj[tid][kk2] != 0);
        s_di[tid] = (d > 0) ? 1.f / (float)d : 0.f;
    }
    __syncthreads();

    {   // phase A3: gather-accumulate; thread = (node ln, channels c8..c8+7)
        int c8 = k << 3;
        float s[NM][8];
        #pragma unroll
        for (int m = 0; m < NM; m++)
            #pragma unroll
            for (int j = 0; j < 8; j++) s[m][j] = 0.f;

        #pragma unroll
        for (int kk2 = 0; kk2 < NKN; kk2++) {
            int a = s_adj[ln][kk2];                // uniform over node's 16 threads
            if (a != 0) {
                float p[8];
                if (BF16G) {
                    u16x8 pv = *(const u16x8*)((const unsigned short*)xb +
                                               (long)(b * NN + a - 1) * NC + c8);
                    #pragma unroll
                    for (int j = 0; j < 8; j++) p[j] = bf2f(pv[j]);
                } else {
                    const float* px = x + (long)(b * NN + a - 1) * NC + c8;
                    float4 p0 = *(const float4*)px;
                    float4 p1 = *(const float4*)(px + 4);
                    p[0]=p0.x; p[1]=p0.y; p[2]=p0.z; p[3]=p0.w;
                    p[4]=p1.x; p[5]=p1.y; p[6]=p1.z; p[7]=p1.w;
                }
                float q[NM];
                #pragma unroll
                for (int m = 0; m < NM; m++) q[m] = s_q[ln][kk2][m];
                #pragma unroll
                for (int m = 0; m < NM; m++)
                    #pragma unroll
                    for (int j = 0; j < 8; j++) s[m][j] += q[m] * p[j];
            }
        }
        float di = s_di[ln];
        #pragma unroll
        for (int m = 0; m < NM; m++) {
            u16x8 ov;
            #pragma unroll
            for (int j = 0; j < 8; j++) {
                union { unsigned short h; __hip_bfloat16 b; } cv2;
                cv2.b = __float2bfloat16(s[m][j] * di);
                ov[j] = cv2.h;
            }
            *(u16x8*)(&s_S[ln][m * NC + c8]) = ov;
        }
    }
    __syncthreads();   // S' ready; drains chunk-0 DMA too

    // ---------------- phase B: GEMM 32x1152 @ 1152x128 ----------------
    int lane = tid & 63;
    int lr = lane & 15;
    int quad = lane >> 4;
    int mt = wave >> 2;        // M-tile (16 rows)
    int w4 = wave & 3;         // col-tile pair {2*w4, 2*w4+1}
    f32x4 acc0 = (f32x4){0.f,0.f,0.f,0.f};
    f32x4 acc1 = (f32x4){0.f,0.f,0.f,0.f};
    const short* aRow = &s_S[mt * 16 + lr][quad * 8];

    for (int kc = 0; kc < NKC; kc++) {
        int buf = kc & 1;
        if (kc + 1 < NKC) {
            const short* src = wg + (kc + 1) * 4096 + tid * 8;
            __builtin_amdgcn_global_load_lds((const AS1 void*)src,
                                             (AS3 void*)&sB[buf ^ 1][wave * 512], 16, 0, 0);
        }
        bf16x8 afrag = *(const bf16x8*)(aRow + kc * 32);
        bf16x8 b0 = *(const bf16x8*)(&sB[buf][((w4 * 2) * 16 + lr) * 32 + quad * 8]);
        acc0 = __builtin_amdgcn_mfma_f32_16x16x32_bf16(afrag, b0, acc0, 0, 0, 0);
        bf16x8 b1 = *(const bf16x8*)(&sB[buf][((w4 * 2 + 1) * 16 + lr) * 32 + quad * 8]);
        acc1 = __builtin_amdgcn_mfma_f32_16x16x32_bf16(afrag, b1, acc1, 0, 0, 0);
        __syncthreads();       // readers done with buf; prefetch into buf^1 drained
    }

    // epilogue: D row = quad*4 + r, col = ct*16 + lr
    int col0 = w4 * 32 + lr;
    int col1 = col0 + 16;
    float bb0 = bv[col0];
    float bb1 = bv[col1];
    int rbase = node0 + mt * 16 + quad * 4;
    #pragma unroll
    for (int r = 0; r < 4; r++) {
        out[(long)(rbase + r) * NO + col0] = acc0[r] + bb0;
        out[(long)(rbase + r) * NO + col1] = acc1[r] + bb1;
    }
}

extern "C" void kernel_launch(void* const* d_in, const int* in_sizes, int n_in,
                              void* d_out, int out_size, void* d_ws, size_t ws_size,
                              hipStream_t stream) {
    const float* x   = (const float*)d_in[0];   // (B,N,C)
    const int*   adj = (const int*)  d_in[1];   // (N,K)
    const float* W   = (const float*)d_in[2];   // (M,O,C)
    const float* bv  = (const float*)d_in[3];   // (O,)
    const float* u   = (const float*)d_in[4];   // (M,C)
    const float* cv  = (const float*)d_in[5];   // (M,)
    float* out = (float*)d_out;

    char* ws = (char*)d_ws;
    float* y = (float*)ws;                                     // 1,440,000 B
    __hip_bfloat16* Wg = (__hip_bfloat16*)(ws + 1440000);      //   294,912 B
    __hip_bfloat16* xb = (__hip_bfloat16*)(ws + 1734912);      // 10,240,000 B (16B-aligned)
    bool use_xb = (ws_size >= (size_t)11974912);

    prep_kernel<<<NR / 4 + 576, 256, 0, stream>>>(x, u, W, y, use_xb ? xb : nullptr, Wg,
                                                  use_xb ? 1 : 0);
    if (use_xb)
        fused_kernel<true><<<NR / NPB, 512, 0, stream>>>(x, xb, adj, y, cv, Wg, bv, out);
    else
        fused_kernel<false><<<NR / NPB, 512, 0, stream>>>(x, xb, adj, y, cv, Wg, bv, out);
}

// Round 5
// 177.316 us; speedup vs baseline: 1.2946x; 1.2946x over previous
//
#include <hip/hip_runtime.h>
#include <hip/hip_bf16.h>

#define NB 2
#define NN 20000
#define NKN 16          // neighbors per node
#define NC 128          // C_IN
#define NM 9            // M kernels
#define NO 128          // C_OUT
#define NR (NB*NN)      // 40000 rows
#define KK (NM*NC)      // 1152 GEMM reduce dim
#define NKC (KK/32)     // 36 K-chunks of 32
#define NPB 16          // nodes per fused block (20000 % 16 == 0 -> no batch straddle)

typedef short bf16x8 __attribute__((ext_vector_type(8)));
typedef float f32x4 __attribute__((ext_vector_type(4)));
typedef unsigned short u16x8 __attribute__((ext_vector_type(8)));

__device__ inline float bf2f(unsigned short h) {
    union { unsigned int u; float f; } v; v.u = ((unsigned int)h) << 16; return v.f;
}

// ---------------- Kernel 1: prep = ycalc (+xb emit) | wprep, by block range ----------
__global__ __launch_bounds__(256) void prep_kernel(const float* __restrict__ x,
                                                   const float* __restrict__ u,
                                                   const float* __restrict__ W,
                                                   float* __restrict__ y,
                                                   __hip_bfloat16* __restrict__ xb,
                                                   __hip_bfloat16* __restrict__ Wg,
                                                   int use_xb) {
    if (blockIdx.x < NR / 4) {
        __shared__ float u_l[NM * NC];
        for (int t = threadIdx.x; t < NM * NC; t += 256) u_l[t] = u[t];
        __syncthreads();
        int wave = threadIdx.x >> 6;
        int lane = threadIdx.x & 63;
        int node = blockIdx.x * 4 + wave;
        float xv0 = x[node * NC + lane];
        float xv1 = x[node * NC + 64 + lane];
        if (use_xb) {
            xb[node * NC + lane]      = __float2bfloat16(xv0);
            xb[node * NC + 64 + lane] = __float2bfloat16(xv1);
        }
        #pragma unroll
        for (int m = 0; m < NM; m++) {
            float p = xv0 * u_l[m * NC + lane] + xv1 * u_l[m * NC + 64 + lane];
            #pragma unroll
            for (int off = 32; off > 0; off >>= 1) p += __shfl_xor(p, off, 64);
            if (lane == 0) y[node * NM + m] = p;
        }
    } else {
        // Wg[((kk/32)*128 + o)*32 + (kk%32)] = bf16(W[m][o][c]), kk = m*128+c
        int t = (blockIdx.x - NR / 4) * 256 + threadIdx.x;   // t < 1152*128
        int kk = t >> 7;
        int o = t & 127;
        int m = kk >> 7;
        int c = kk & 127;
        float v = W[m * 16384 + o * 128 + c];
        Wg[((kk >> 5) * 128 + o) * 32 + (kk & 31)] = __float2bfloat16(v);
    }
}

// ---------------- Kernel 2: fused edge-softmax + aggregate + MFMA GEMM --------------
// Block = 16 nodes, 256 threads (4 waves), ~47KB LDS -> 3 blocks/CU.
// Phase A: logits (Y-trick) + softmax + deg_inv; gather-accumulate S'(16x1152) into
//          XOR-swizzled LDS (bf16, 16B granules, g' = g ^ (row&7) -> conflict-free).
// Phase B: out[16x128] = S' x Wg + b; barrier-free: A-frags from LDS, B-frags
//          direct from global (Wg is 288KB, L2-resident), 2 MFMA/kc/wave.
template<bool BF16G>
__global__ __launch_bounds__(256, 3) void fused_kernel(const float* __restrict__ x,
                                                       const __hip_bfloat16* __restrict__ xb,
                                                       const int* __restrict__ adj,
                                                       const float* __restrict__ y,
                                                       const float* __restrict__ cv,
                                                       const __hip_bfloat16* __restrict__ Wg,
                                                       const float* __restrict__ bv,
                                                       float* __restrict__ out) {
    __shared__ __align__(16) short s_S[NPB * KK];  // 36,864 B, swizzled granules
    __shared__ int   s_adj[NPB][NKN];              //  1,024 B
    __shared__ float s_q[NPB][NKN][NM];            //  9,216 B
    __shared__ float s_di[NPB];                    //     64 B

    int tid = threadIdx.x;
    int node0 = blockIdx.x * NPB;
    int b = node0 / NN;
    int n0 = node0 - b * NN;

    int ln = tid >> 4, k = tid & 15;               // 256 = 16 nodes x 16 edges
    s_adj[ln][k] = adj[(n0 + ln) * NKN + k];
    __syncthreads();

    {   // phase A2: logits (Y-trick) + softmax for edge (ln, k)
        int a = s_adj[ln][k];
        const float* yn = y + (node0 + ln) * NM;
        float l[NM];
        if (a != 0) {
            const float* ya = y + (long)(b * NN + a - 1) * NM;
            #pragma unroll
            for (int m = 0; m < NM; m++) l[m] = yn[m] - ya[m] + cv[m];
        } else {
            #pragma unroll
            for (int m = 0; m < NM; m++) l[m] = yn[m] + cv[m];
        }
        float mx = l[0];
        #pragma unroll
        for (int m = 1; m < NM; m++) mx = fmaxf(mx, l[m]);
        float e[NM]; float sum = 0.f;
        #pragma unroll
        for (int m = 0; m < NM; m++) { e[m] = expf(l[m] - mx); sum += e[m]; }
        float inv = 1.f / sum;
        #pragma unroll
        for (int m = 0; m < NM; m++) s_q[ln][k][m] = e[m] * inv;
    }
    if (tid < NPB) {
        int d = 0;
        #pragma unroll
        for (int kk2 = 0; kk2 < NKN; kk2++) d += (s_adj[tid][kk2] != 0);
        s_di[tid] = (d > 0) ? 1.f / (float)d : 0.f;
    }
    __syncthreads();

    {   // phase A3: gather-accumulate; thread = (node ln, channels k*8..k*8+7)
        int c8 = k << 3;
        float s[NM][8];
        #pragma unroll
        for (int m = 0; m < NM; m++)
            #pragma unroll
            for (int j = 0; j < 8; j++) s[m][j] = 0.f;

        #pragma unroll
        for (int kk2 = 0; kk2 < NKN; kk2++) {
            int a = s_adj[ln][kk2];                // uniform over node's 16 threads
            if (a != 0) {
                float p[8];
                if (BF16G) {
                    u16x8 pv = *(const u16x8*)((const unsigned short*)xb +
                                               (long)(b * NN + a - 1) * NC + c8);
                    #pragma unroll
                    for (int j = 0; j < 8; j++) p[j] = bf2f(pv[j]);
                } else {
                    const float* px = x + (long)(b * NN + a - 1) * NC + c8;
                    float4 p0 = *(const float4*)px;
                    float4 p1 = *(const float4*)(px + 4);
                    p[0]=p0.x; p[1]=p0.y; p[2]=p0.z; p[3]=p0.w;
                    p[4]=p1.x; p[5]=p1.y; p[6]=p1.z; p[7]=p1.w;
                }
                float q[NM];
                #pragma unroll
                for (int m = 0; m < NM; m++) q[m] = s_q[ln][kk2][m];
                #pragma unroll
                for (int m = 0; m < NM; m++)
                    #pragma unroll
                    for (int j = 0; j < 8; j++) s[m][j] += q[m] * p[j];
            }
        }
        float di = s_di[ln];
        #pragma unroll
        for (int m = 0; m < NM; m++) {
            u16x8 ov;
            #pragma unroll
            for (int j = 0; j < 8; j++) {
                union { unsigned short h; __hip_bfloat16 b; } cv2;
                cv2.b = __float2bfloat16(s[m][j] * di);
                ov[j] = cv2.h;
            }
            int g = m * 16 + k;                    // 16B granule index within row
            int gs = g ^ (ln & 7);                 // XOR swizzle -> bank spread
            *(u16x8*)(&s_S[ln * KK + gs * 8]) = ov;
        }
    }
    __syncthreads();   // S' ready — the ONLY barrier before the GEMM

    // ---------------- phase B: GEMM 16x1152 @ 1152x128, barrier-free ----------------
    int wave = tid >> 6;
    int lane = tid & 63;
    int lr = lane & 15;        // A row / B col-in-tile
    int quad = lane >> 4;      // k-group
    const short* wg = reinterpret_cast<const short*>(Wg);
    f32x4 acc0 = (f32x4){0.f,0.f,0.f,0.f};
    f32x4 acc1 = (f32x4){0.f,0.f,0.f,0.f};
    int ct0 = wave * 2;        // this wave's col-tiles: ct0, ct0+1

    #pragma unroll 4
    for (int kc = 0; kc < NKC; kc++) {
        int g = kc * 4 + quad;                     // A granule
        int gs = g ^ (lr & 7);
        bf16x8 afrag = *(const bf16x8*)(&s_S[lr * KK + gs * 8]);
        bf16x8 b0 = *(const bf16x8*)(wg + ((kc * 128) + ct0 * 16 + lr) * 32 + quad * 8);
        bf16x8 b1 = *(const bf16x8*)(wg + ((kc * 128) + (ct0 + 1) * 16 + lr) * 32 + quad * 8);
        acc0 = __builtin_amdgcn_mfma_f32_16x16x32_bf16(afrag, b0, acc0, 0, 0, 0);
        acc1 = __builtin_amdgcn_mfma_f32_16x16x32_bf16(afrag, b1, acc1, 0, 0, 0);
    }

    // epilogue: D row = quad*4 + r, col = ct*16 + lr
    int col0 = ct0 * 16 + lr;
    int col1 = col0 + 16;
    float bb0 = bv[col0];
    float bb1 = bv[col1];
    int rbase = node0 + quad * 4;
    #pragma unroll
    for (int r = 0; r < 4; r++) {
        out[(long)(rbase + r) * NO + col0] = acc0[r] + bb0;
        out[(long)(rbase + r) * NO + col1] = acc1[r] + bb1;
    }
}

extern "C" void kernel_launch(void* const* d_in, const int* in_sizes, int n_in,
                              void* d_out, int out_size, void* d_ws, size_t ws_size,
                              hipStream_t stream) {
    const float* x   = (const float*)d_in[0];   // (B,N,C)
    const int*   adj = (const int*)  d_in[1];   // (N,K)
    const float* W   = (const float*)d_in[2];   // (M,O,C)
    const float* bv  = (const float*)d_in[3];   // (O,)
    const float* u   = (const float*)d_in[4];   // (M,C)
    const float* cv  = (const float*)d_in[5];   // (M,)
    float* out = (float*)d_out;

    char* ws = (char*)d_ws;
    float* y = (float*)ws;                                     // 1,440,000 B
    __hip_bfloat16* Wg = (__hip_bfloat16*)(ws + 1440000);      //   294,912 B
    __hip_bfloat16* xb = (__hip_bfloat16*)(ws + 1734912);      // 10,240,000 B (16B-aligned)
    bool use_xb = (ws_size >= (size_t)11974912);

    prep_kernel<<<NR / 4 + 576, 256, 0, stream>>>(x, u, W, y, use_xb ? xb : nullptr, Wg,
                                                  use_xb ? 1 : 0);
    if (use_xb)
        fused_kernel<true><<<NR / NPB, 256, 0, stream>>>(x, xb, adj, y, cv, Wg, bv, out);
    else
        fused_kernel<false><<<NR / NPB, 256, 0, stream>>>(x, xb, adj, y, cv, Wg, bv, out);
}

// Round 6
// 163.432 us; speedup vs baseline: 1.4045x; 1.0850x over previous
//
#include <hip/hip_runtime.h>
#include <hip/hip_bf16.h>

#define NB 2
#define NN 20000
#define NKN 16          // neighbors per node
#define NC 128          // C_IN
#define NM 9            // M kernels
#define NO 128          // C_OUT
#define NR (NB*NN)      // 40000 rows
#define KK (NM*NC)      // 1152 GEMM reduce dim
#define NKC (KK/32)     // 36 K-chunks of 32
#define NPB 16          // nodes per fused block
#define YS 12           // padded y row stride (floats) -> float4-aligned

typedef short bf16x8 __attribute__((ext_vector_type(8)));
typedef float f32x4 __attribute__((ext_vector_type(4)));
typedef float f32x2 __attribute__((ext_vector_type(2)));
typedef unsigned short u16x8 __attribute__((ext_vector_type(8)));

__device__ inline f32x2 bfpair(unsigned int w) {   // [lo16, hi16] bf16 -> float2
    union { unsigned int u; float f; } lo, hi;
    lo.u = w << 16; hi.u = w & 0xFFFF0000u;
    return (f32x2){lo.f, hi.f};
}

// ---------------- Kernel 1: prep = ycalc (+xb emit) | wprep, by block range ----------
__global__ __launch_bounds__(256) void prep_kernel(const float* __restrict__ x,
                                                   const float* __restrict__ u,
                                                   const float* __restrict__ W,
                                                   float* __restrict__ y,
                                                   __hip_bfloat16* __restrict__ xb,
                                                   __hip_bfloat16* __restrict__ Wg,
                                                   int use_xb) {
    if (blockIdx.x < NR / 4) {
        __shared__ float u_l[NM * NC];
        for (int t = threadIdx.x; t < NM * NC; t += 256) u_l[t] = u[t];
        __syncthreads();
        int wave = threadIdx.x >> 6;
        int lane = threadIdx.x & 63;
        int node = blockIdx.x * 4 + wave;
        float xv0 = x[node * NC + lane];
        float xv1 = x[node * NC + 64 + lane];
        if (use_xb) {
            xb[node * NC + lane]      = __float2bfloat16(xv0);
            xb[node * NC + 64 + lane] = __float2bfloat16(xv1);
        }
        #pragma unroll
        for (int m = 0; m < NM; m++) {
            float p = xv0 * u_l[m * NC + lane] + xv1 * u_l[m * NC + 64 + lane];
            #pragma unroll
            for (int off = 32; off > 0; off >>= 1) p += __shfl_xor(p, off, 64);
            if (lane == 0) y[node * YS + m] = p;
        }
    } else {
        // Wg[((kk/32)*128 + o)*32 + (kk%32)] = bf16(W[m][o][c]), kk = m*128+c
        int t = (blockIdx.x - NR / 4) * 256 + threadIdx.x;   // t < 1152*128
        int kk = t >> 7;
        int o = t & 127;
        int m = kk >> 7;
        int c = kk & 127;
        float v = W[m * 16384 + o * 128 + c];
        Wg[((kk >> 5) * 128 + o) * 32 + (kk & 31)] = __float2bfloat16(v);
    }
}

// ---------------- Kernel 2: fused edge-softmax + aggregate + MFMA GEMM --------------
// Block = 16 nodes, 256 threads (4 waves), 50,176 B LDS -> 3 blocks/CU.
// A1+A2 (no barrier between): adj + logits (Y-trick) + softmax; q stored *pre-zeroed*
//   for padding edges so phase A3 is branch-free.
// barrier -> A3: gather-accumulate, loads batched 8-deep, v_pk_fma_f32 via float2,
//   deg computed inline; S' -> XOR-swizzled LDS (bf16).
// barrier -> B: out[16x128] = S' x Wg + b, barrier-free MFMA, B-frags from L2.
template<bool BF16G>
__global__ __launch_bounds__(256, 3) void fused_kernel(const float* __restrict__ x,
                                                       const __hip_bfloat16* __restrict__ xb,
                                                       const int* __restrict__ adj,
                                                       const float* __restrict__ y,
                                                       const float* __restrict__ cv,
                                                       const __hip_bfloat16* __restrict__ Wg,
                                                       const float* __restrict__ bv,
                                                       float* __restrict__ out) {
    __shared__ __align__(16) short s_S[NPB * KK];  // 36,864 B, swizzled granules
    __shared__ int   s_adj[NPB][NKN];              //  1,024 B
    __shared__ __align__(16) float s_q[NPB][NKN][12]; // 12,288 B (9 used, pad 12)

    int tid = threadIdx.x;
    int node0 = blockIdx.x * NPB;
    int b = node0 / NN;
    int n0 = node0 - b * NN;
    int ln = tid >> 4, k = tid & 15;               // 256 = 16 nodes x 16 edges

    // ---- A1: adj (own element kept in register) ----
    int a = adj[(n0 + ln) * NKN + k];
    s_adj[ln][k] = a;

    // ---- A2: logits via Y-trick (branch-free loads) + softmax; q pre-zeroed ----
    {
        const float* yn = y + (long)(node0 + ln) * YS;
        const float* ya = y + (long)(b * NN + ((a > 0) ? a - 1 : 0)) * YS;
        float4 yn0 = *(const float4*)yn;
        float4 yn1 = *(const float4*)(yn + 4);
        float  yn8 = yn[8];
        float4 ya0 = *(const float4*)ya;
        float4 ya1 = *(const float4*)(ya + 4);
        float  ya8 = ya[8];
        float sel = (a > 0) ? 1.f : 0.f;
        float l[NM];
        l[0] = yn0.x - sel * ya0.x + cv[0];
        l[1] = yn0.y - sel * ya0.y + cv[1];
        l[2] = yn0.z - sel * ya0.z + cv[2];
        l[3] = yn0.w - sel * ya0.w + cv[3];
        l[4] = yn1.x - sel * ya1.x + cv[4];
        l[5] = yn1.y - sel * ya1.y + cv[5];
        l[6] = yn1.z - sel * ya1.z + cv[6];
        l[7] = yn1.w - sel * ya1.w + cv[7];
        l[8] = yn8   - sel * ya8   + cv[8];
        float mx = l[0];
        #pragma unroll
        for (int m = 1; m < NM; m++) mx = fmaxf(mx, l[m]);
        float e[NM]; float sum = 0.f;
        #pragma unroll
        for (int m = 0; m < NM; m++) { e[m] = expf(l[m] - mx); sum += e[m]; }
        float qs = (a > 0) ? (1.f / sum) : 0.f;    // padding edge -> q == 0
        #pragma unroll
        for (int m = 0; m < NM; m++) s_q[ln][k][m] = e[m] * qs;
    }
    __syncthreads();

    // ---- A3: branch-free pipelined gather-accumulate ----
    {
        int c8 = k << 3;
        int idx[NKN]; int d = 0;
        #pragma unroll
        for (int j = 0; j < NKN; j++) {
            int aa = s_adj[ln][j];
            d += (aa > 0);
            idx[j] = (aa > 0) ? aa - 1 : 0;        // safe index; q=0 kills contribution
        }
        float di = (d > 0) ? 1.f / (float)d : 0.f;

        f32x2 s2[NM][4];
        #pragma unroll
        for (int m = 0; m < NM; m++)
            #pragma unroll
            for (int j = 0; j < 4; j++) s2[m][j] = (f32x2){0.f, 0.f};

        const int GSZ = BF16G ? 8 : 4;
        #pragma unroll
        for (int g = 0; g < NKN / (BF16G ? 8 : 4); g++) {
            uint4  pw[8];
            float4 fa[4], fb[4];
            if (BF16G) {
                #pragma unroll
                for (int j = 0; j < 8; j++)
                    pw[j] = *(const uint4*)((const unsigned short*)xb +
                                            (long)(b * NN + idx[g * 8 + j]) * NC + c8);
            } else {
                #pragma unroll
                for (int j = 0; j < 4; j++) {
                    const float* px = x + (long)(b * NN + idx[g * 4 + j]) * NC + c8;
                    fa[j] = *(const float4*)px;
                    fb[j] = *(const float4*)(px + 4);
                }
            }
            #pragma unroll
            for (int j = 0; j < (BF16G ? 8 : 4); j++) {
                int kk2 = g * GSZ + j;
                f32x2 p0, p1, p2, p3;
                if (BF16G) {
                    p0 = bfpair(pw[j].x); p1 = bfpair(pw[j].y);
                    p2 = bfpair(pw[j].z); p3 = bfpair(pw[j].w);
                } else {
                    p0 = (f32x2){fa[j].x, fa[j].y}; p1 = (f32x2){fa[j].z, fa[j].w};
                    p2 = (f32x2){fb[j].x, fb[j].y}; p3 = (f32x2){fb[j].z, fb[j].w};
                }
                const float* qr = s_q[ln][kk2];
                float4 qa = *(const float4*)qr;
                float4 qb = *(const float4*)(qr + 4);
                float  q8 = qr[8];
                #define ACC(mi, qv) { f32x2 qq = (f32x2){(qv), (qv)};           \
                    s2[mi][0] += qq * p0; s2[mi][1] += qq * p1;                 \
                    s2[mi][2] += qq * p2; s2[mi][3] += qq * p3; }
                ACC(0, qa.x) ACC(1, qa.y) ACC(2, qa.z) ACC(3, qa.w)
                ACC(4, qb.x) ACC(5, qb.y) ACC(6, qb.z) ACC(7, qb.w) ACC(8, q8)
                #undef ACC
            }
        }

        #pragma unroll
        for (int m = 0; m < NM; m++) {
            u16x8 ov;
            #pragma unroll
            for (int j = 0; j < 4; j++) {
                union { unsigned short h; __hip_bfloat16 bb; } c0, c1;
                c0.bb = __float2bfloat16(s2[m][j][0] * di);
                c1.bb = __float2bfloat16(s2[m][j][1] * di);
                ov[j * 2]     = c0.h;
                ov[j * 2 + 1] = c1.h;
            }
            int g = m * 16 + k;                    // 16B granule index within row
            int gs = g ^ (ln & 7);                 // XOR swizzle -> bank spread
            *(u16x8*)(&s_S[ln * KK + gs * 8]) = ov;
        }
    }
    __syncthreads();   // S' ready — the only other barrier

    // ---------------- phase B: GEMM 16x1152 @ 1152x128, barrier-free ----------------
    int wave = tid >> 6;
    int lane = tid & 63;
    int lr = lane & 15;        // A row / B col-in-tile
    int quad = lane >> 4;      // k-group
    const short* wg = reinterpret_cast<const short*>(Wg);
    f32x4 acc0 = (f32x4){0.f,0.f,0.f,0.f};
    f32x4 acc1 = (f32x4){0.f,0.f,0.f,0.f};
    int ct0 = wave * 2;        // this wave's col-tiles: ct0, ct0+1

    #pragma unroll 4
    for (int kc = 0; kc < NKC; kc++) {
        int g = kc * 4 + quad;                     // A granule
        int gs = g ^ (lr & 7);
        bf16x8 afrag = *(const bf16x8*)(&s_S[lr * KK + gs * 8]);
        bf16x8 b0 = *(const bf16x8*)(wg + ((kc * 128) + ct0 * 16 + lr) * 32 + quad * 8);
        bf16x8 b1 = *(const bf16x8*)(wg + ((kc * 128) + (ct0 + 1) * 16 + lr) * 32 + quad * 8);
        acc0 = __builtin_amdgcn_mfma_f32_16x16x32_bf16(afrag, b0, acc0, 0, 0, 0);
        acc1 = __builtin_amdgcn_mfma_f32_16x16x32_bf16(afrag, b1, acc1, 0, 0, 0);
    }

    // epilogue: D row = quad*4 + r, col = ct*16 + lr
    int col0 = ct0 * 16 + lr;
    int col1 = col0 + 16;
    float bb0 = bv[col0];
    float bb1 = bv[col1];
    int rbase = node0 + quad * 4;
    #pragma unroll
    for (int r = 0; r < 4; r++) {
        out[(long)(rbase + r) * NO + col0] = acc0[r] + bb0;
        out[(long)(rbase + r) * NO + col1] = acc1[r] + bb1;
    }
}

extern "C" void kernel_launch(void* const* d_in, const int* in_sizes, int n_in,
                              void* d_out, int out_size, void* d_ws, size_t ws_size,
                              hipStream_t stream) {
    const float* x   = (const float*)d_in[0];   // (B,N,C)
    const int*   adj = (const int*)  d_in[1];   // (N,K)
    const float* W   = (const float*)d_in[2];   // (M,O,C)
    const float* bv  = (const float*)d_in[3];   // (O,)
    const float* u   = (const float*)d_in[4];   // (M,C)
    const float* cv  = (const float*)d_in[5];   // (M,)
    float* out = (float*)d_out;

    char* ws = (char*)d_ws;
    float* y = (float*)ws;                                     // 40000*12*4 = 1,920,000 B
    __hip_bfloat16* Wg = (__hip_bfloat16*)(ws + 1920000);      //   294,912 B
    __hip_bfloat16* xb = (__hip_bfloat16*)(ws + 2214912);      // 10,240,000 B (16B-aligned)
    bool use_xb = (ws_size >= (size_t)12454912);

    prep_kernel<<<NR / 4 + 576, 256, 0, stream>>>(x, u, W, y, use_xb ? xb : nullptr, Wg,
                                                  use_xb ? 1 : 0);
    if (use_xb)
        fused_kernel<true><<<NR / NPB, 256, 0, stream>>>(x, xb, adj, y, cv, Wg, bv, out);
    else
        fused_kernel<false><<<NR / NPB, 256, 0, stream>>>(x, xb, adj, y, cv, Wg, bv, out);
}